// Round 1
// 1040.992 us; speedup vs baseline: 1.0623x; 1.0623x over previous
//
#include <hip/hip_runtime.h>

#define N_ROWS 100000
#define HID 256
#define NCLASS 64
#define KPAD 2816
#define NTILE 44
#define BN_EPS 1e-5f

typedef unsigned short u16;
typedef unsigned int u32;
typedef __bf16 bf16x8 __attribute__((ext_vector_type(8)));
typedef float floatx4 __attribute__((ext_vector_type(4)));
typedef float f32x4u __attribute__((ext_vector_type(4), aligned(4)));

union FragU { bf16x8 v; uint4 u; u16 s[8]; };
union BfBits { __bf16 b; u16 s; };

struct GemmArgs {
    const float* feat[8];
    const float* emb[8];
};

// padded-K channel offsets (each channel padded to multiple of 64)
// dims {334,512,128,745,256,600,64,64} -> pads {384,512,128,768,256,640,64,64}
// All offsets are multiples of 64, so one K-tile never spans two channels.
__constant__ int c_POFF[9] = {0, 384, 896, 1024, 1792, 2048, 2688, 2752, 2816};
__constant__ int c_KDIM[8] = {334, 512, 128, 745, 256, 600, 64, 64};

// global_load_lds, 16B per lane: LDS dest must be wave-uniform base + lane*16 (it is:
// dest = smB + it*4096 + tid*16); global source is per-lane (pre-swizzled in k_prep1).
__device__ __forceinline__ void gll16(const void* g, void* l) {
    __builtin_amdgcn_global_load_lds((const __attribute__((address_space(1))) u32*)g,
                                     (__attribute__((address_space(3))) u32*)l, 16, 0, 0);
}

// ---------------- prep 0: gate probs + zero global stats ----------------
__global__ void k_prep0(const float* __restrict__ alpha, const float* __restrict__ gumbels,
                        const int* __restrict__ es, float* __restrict__ wsf) {
    int tid = threadIdx.x;
    if (tid < 128) wsf[8 + tid] = 0.f;   // gstats[128] at wsf+8
    if (tid == 0) {
        float w[8], mx = -1e30f;
        for (int i = 0; i < 8; ++i) { w[i] = alpha[es[i]]; mx = fmaxf(mx, w[i]); }
        float se = 0.f;
        for (int i = 0; i < 8; ++i) se += expf(w[i] - mx);
        float lse = logf(se) + mx;
        float t[8], mt = -1e30f;
        for (int i = 0; i < 8; ++i) { t[i] = (w[i] - lse + gumbels[i]); mt = fmaxf(mt, t[i]); } // TAU=1
        float p[8], ss = 0.f;
        for (int i = 0; i < 8; ++i) { p[i] = expf(t[i] - mt); ss += p[i]; }
        for (int i = 0; i < 8; ++i) wsf[i] = p[i] / ss;
    }
}

// ---------------- prep 1: build WcTpre = per-K-tile, pre-swizzled, LDS-image of the
// combined weight matrix (scaled emb, bf16), tile t is a contiguous 32KB chunk laid out
// exactly as k_gemm1 wants it in LDS:  chunk[ci] (ci = n*8+slot, 16B each) holds logical
// WcT[n][t*64 + (slot ^ (n&7))*8 .. +8].  Also wT[64][256] bf16 copy of w_out.
__global__ __launch_bounds__(256) void k_prep1(GemmArgs ga, const float* __restrict__ w_out,
                                               const float* __restrict__ wsf,
                                               u16* __restrict__ WcTpre, u16* __restrict__ wT) {
    const int t = blockIdx.x, n = threadIdx.x;
    if (t < NTILE) {
        int c = 0;
        #pragma unroll
        for (int i = 1; i < 8; ++i) c += (t * 64 >= c_POFF[i]);
        const int Kc = c_KDIM[c];
        const int lb = t * 64 - c_POFF[c];
        const float sc = wsf[c];
        const float* ep = ga.emb[c] + n;          // reads coalesced across threads (n)
        u16* dst = WcTpre + t * 16384 + n * 64;   // thread writes 128B contiguous
        #pragma unroll
        for (int slot = 0; slot < 8; ++slot) {
            const int q8 = slot ^ (n & 7);        // inverse of the read-side XOR swizzle
            FragU f;
            #pragma unroll
            for (int j = 0; j < 8; ++j) {
                const int l = lb + q8 * 8 + j;
                float v = (l < Kc) ? sc * ep[l * HID] : 0.f;
                f.v[j] = (__bf16)v;
            }
            ((uint4*)dst)[slot] = f.u;
        }
    } else {
        // one block: w_out [64][256] fp32 -> bf16, coalesced
        #pragma unroll 4
        for (int cls = 0; cls < 64; ++cls) {
            BfBits u; u.b = (__bf16)w_out[cls * HID + n];
            wT[cls * HID + n] = u.s;
        }
    }
}

// ---------------- GEMM1 (64x256 tile, double-buffered 1-barrier pipeline)
//                  + PReLU + GEMM2 (x @ w_out^T) + stats ----------------
__global__ __launch_bounds__(256) void k_gemm1(GemmArgs ga, const u16* __restrict__ WcTpre,
                                               const u16* __restrict__ wT,
                                               const float* __restrict__ prelu_a,
                                               float* __restrict__ out,
                                               float* __restrict__ gstats) {
    // LDS budget: 2*8192 (A dbuf) + 2*32768 (B dbuf) = 81920 B exactly -> 2 blocks/CU.
    // sstats aliases smA[0] (only live in the epilogue, after the last tile's barrier).
    __shared__ __align__(16) char sm[81920];
    #define SMA(b) (sm + (b) * 8192)
    #define SMB(b) (sm + 16384 + (b) * 32768)

    const int tid = threadIdx.x;
    const int lane = tid & 63;
    const int quad = lane >> 4;
    const int l15 = lane & 15;
    const int wave = tid >> 6;
    const int row0 = blockIdx.x * 64;

    floatx4 acc[4][4];
    #pragma unroll
    for (int i = 0; i < 4; ++i)
        #pragma unroll
        for (int j = 0; j < 4; ++j)
            acc[i][j] = (floatx4){0.f, 0.f, 0.f, 0.f};

    // ---- prologue: stage tile 0 (A: reg->cvt->LDS, B: global_load_lds) ----
    {
        const int Kc = c_KDIM[0];               // tile 0 is channel 0
        const float* fpb = ga.feat[0];
        #pragma unroll
        for (int i = 0; i < 2; ++i) {
            int o = tid + i * 256;
            int row = o >> 3, oct = o & 7;
            int r = row0 + row, lk = oct * 8;
            const float* fp = fpb + r * Kc + lk;
            float vv[8];
            if (r < N_ROWS && lk + 8 <= Kc) {
                f32x4u a0 = *(const f32x4u*)fp;
                f32x4u a1 = *(const f32x4u*)(fp + 4);
                vv[0] = a0.x; vv[1] = a0.y; vv[2] = a0.z; vv[3] = a0.w;
                vv[4] = a1.x; vv[5] = a1.y; vv[6] = a1.z; vv[7] = a1.w;
            } else {
                #pragma unroll
                for (int j = 0; j < 8; ++j)
                    vv[j] = (r < N_ROWS && lk + j < Kc) ? fp[j] : 0.f;
            }
            FragU f;
            #pragma unroll
            for (int j = 0; j < 8; ++j) f.v[j] = (__bf16)vv[j];
            *(uint4*)(SMA(0) + row * 128 + ((oct ^ (row & 7)) << 4)) = f.u;
        }
        const u16* src = WcTpre;                // tile 0 chunk, linear copy
        #pragma unroll
        for (int it = 0; it < 8; ++it) {
            int ci = tid + it * 256;
            gll16(src + ci * 8, SMB(0) + ci * 16);
        }
    }
    __syncthreads();                            // drains vmcnt (gll) + lgkm (ds_write)

    float pv[2][8];                             // in-flight A tile (issue-early/write-late)
    for (int t = 0; t < NTILE; ++t) {
        const int cur = t & 1, nxt = cur ^ 1;
        const bool hn = (t + 1 < NTILE);

        if (hn) {
            // ---- issue next A tile: global -> regs (needed only after the MFMAs) ----
            const int k0n = (t + 1) * 64;
            int cn = 0;
            #pragma unroll
            for (int i = 1; i < 8; ++i) cn += (k0n >= c_POFF[i]);
            const int Kcn = c_KDIM[cn];
            const int lkbn = k0n - c_POFF[cn];
            const float* fpb = ga.feat[cn];
            #pragma unroll
            for (int i = 0; i < 2; ++i) {
                int o = tid + i * 256;
                int row = o >> 3, oct = o & 7;
                int r = row0 + row, lk = lkbn + oct * 8;
                const float* fp = fpb + r * Kcn + lk;
                if (r < N_ROWS && lk + 8 <= Kcn) {
                    f32x4u a0 = *(const f32x4u*)fp;
                    f32x4u a1 = *(const f32x4u*)(fp + 4);
                    pv[i][0] = a0.x; pv[i][1] = a0.y; pv[i][2] = a0.z; pv[i][3] = a0.w;
                    pv[i][4] = a1.x; pv[i][5] = a1.y; pv[i][6] = a1.z; pv[i][7] = a1.w;
                } else {
                    #pragma unroll
                    for (int j = 0; j < 8; ++j)
                        pv[i][j] = (r < N_ROWS && lk + j < Kcn) ? fp[j] : 0.f;
                }
            }
            // ---- issue next B tile straight into LDS (no VGPR round-trip) ----
            const u16* src = WcTpre + (t + 1) * 16384;
            #pragma unroll
            for (int it = 0; it < 8; ++it) {
                int ci = tid + it * 256;
                gll16(src + ci * 8, SMB(nxt) + ci * 16);
            }
        }

        // ---- compute current tile: 2 k-steps of 32, 16 MFMA each per wave ----
        const char* sA = SMA(cur);
        const char* sB = SMB(cur);
        #pragma unroll
        for (int ks = 0; ks < 2; ++ks) {
            const int oct = ks * 4 + quad;
            FragU af[4], bfr[4];
            #pragma unroll
            for (int mf = 0; mf < 4; ++mf) {
                int m = mf * 16 + l15;
                af[mf].u = *(const uint4*)(sA + m * 128 + ((oct ^ (m & 7)) << 4));
            }
            #pragma unroll
            for (int nf = 0; nf < 4; ++nf) {
                int n = wave * 64 + nf * 16 + l15;
                bfr[nf].u = *(const uint4*)(sB + n * 128 + ((oct ^ (n & 7)) << 4));
            }
            #pragma unroll
            for (int mf = 0; mf < 4; ++mf)
                #pragma unroll
                for (int nf = 0; nf < 4; ++nf)
                    acc[mf][nf] = __builtin_amdgcn_mfma_f32_16x16x32_bf16(
                        af[mf].v, bfr[nf].v, acc[mf][nf], 0, 0, 0);
        }

        if (hn) {
            // ---- write-late: convert the in-flight A regs, ds_write to the other buffer ----
            #pragma unroll
            for (int i = 0; i < 2; ++i) {
                int o = tid + i * 256;
                int row = o >> 3, oct = o & 7;
                FragU f;
                #pragma unroll
                for (int j = 0; j < 8; ++j) f.v[j] = (__bf16)pv[i][j];
                *(uint4*)(SMA(nxt) + row * 128 + ((oct ^ (row & 7)) << 4)) = f.u;
            }
        }
        __syncthreads();   // single barrier/tile: drains gll(B,nxt) + ds_write(A,nxt)
    }

    // ---- epilogue: PReLU, h -> LDS (A-operand layout, swizzled). h lives in SMB(0). ----
    const float slope = prelu_a[0];
    char* hbuf = SMB(0);
    #pragma unroll
    for (int nf = 0; nf < 4; ++nf) {
        int colg = wave * 64 + nf * 16 + l15;   // k index of h
        int oct = colg >> 3, sub = colg & 7;
        #pragma unroll
        for (int mf = 0; mf < 4; ++mf) {
            #pragma unroll
            for (int r = 0; r < 4; ++r) {
                int row = mf * 16 + quad * 4 + r;
                float x = acc[mf][nf][r];
                float hx = x >= 0.f ? x : slope * x;
                BfBits u; u.b = (__bf16)hx;
                *(u16*)(hbuf + row * 512 + ((oct ^ (row & 7)) << 4) + sub * 2) = u.s;
            }
        }
    }
    float* sstats = (float*)sm;                 // alias smA[0] (dead after main loop)
    if (tid < 128) sstats[tid] = 0.f;
    __syncthreads();

    // ---- GEMM2: z[64 x 64] = h @ w_out^T ; wave w owns rows [16w,16w+16) ----
    floatx4 acc2[4];
    #pragma unroll
    for (int i = 0; i < 4; ++i) acc2[i] = (floatx4){0.f, 0.f, 0.f, 0.f};
    {
        int m = wave * 16 + l15;
        #pragma unroll
        for (int ks = 0; ks < 8; ++ks) {
            int oct = ks * 4 + quad;
            FragU ah;
            ah.u = *(const uint4*)(hbuf + m * 512 + ((oct ^ (m & 7)) << 4));
            #pragma unroll
            for (int nf = 0; nf < 4; ++nf) {
                int cls = nf * 16 + l15;
                FragU bw;
                bw.u = *(const uint4*)(wT + cls * HID + oct * 8);
                acc2[nf] = __builtin_amdgcn_mfma_f32_16x16x32_bf16(ah.v, bw.v, acc2[nf], 0, 0, 0);
            }
        }
    }

    // ---- store z + per-class partial sums ----
    #pragma unroll
    for (int nf = 0; nf < 4; ++nf) {
        int cls = nf * 16 + l15;
        float s1 = 0.f, s2 = 0.f;
        #pragma unroll
        for (int r = 0; r < 4; ++r) {
            int row = wave * 16 + quad * 4 + r;
            int grow = row0 + row;
            float z = acc2[nf][r];
            if (grow < N_ROWS) out[grow * NCLASS + cls] = z;
            s1 += z; s2 += z * z;   // invalid rows give z==0
        }
        s1 += __shfl_xor(s1, 16); s1 += __shfl_xor(s1, 32);
        s2 += __shfl_xor(s2, 16); s2 += __shfl_xor(s2, 32);
        if (quad == 0) {
            atomicAdd(&sstats[cls], s1);
            atomicAdd(&sstats[64 + cls], s2);
        }
    }
    __syncthreads();
    if (tid < 128) atomicAdd(&gstats[tid], sstats[tid]);
    #undef SMA
    #undef SMB
}

// ---------------- stats finalize: sums -> mean / invstd ----------------
__global__ void k_stats(float* __restrict__ wsf) {
    int c = threadIdx.x;
    if (c < 64) {
        float s1 = wsf[8 + c], s2 = wsf[8 + 64 + c];
        float mean = s1 * (1.f / N_ROWS);
        float var = s2 * (1.f / N_ROWS) - mean * mean;
        wsf[8 + c] = mean;
        wsf[8 + 64 + c] = rsqrtf(var + BN_EPS);
    }
}

// ---------------- normalize in place ----------------
__global__ __launch_bounds__(256) void k_norm(float* __restrict__ out, const float* __restrict__ wsf) {
    int idx = blockIdx.x * 256 + threadIdx.x;
    int base = idx * 4;
    int c0 = base & 63;
    floatx4 v = *(floatx4*)(out + base);
    #pragma unroll
    for (int j = 0; j < 4; ++j) {
        float mean = wsf[8 + c0 + j];
        float inv  = wsf[72 + c0 + j];
        v[j] = (v[j] - mean) * inv;
    }
    *(floatx4*)(out + base) = v;
}

extern "C" void kernel_launch(void* const* d_in, const int* in_sizes, int n_in,
                              void* d_out, int out_size, void* d_ws, size_t ws_size,
                              hipStream_t stream) {
    // dict order: feat0,emb0,...,feat5,emb5, lab0,lemb0, lab1,lemb1,
    //             alpha(16), gumbels(17), prelu_a(18), w_out(19), epoch_sampled(20)
    GemmArgs ga;
    const int fidx[8] = {0, 2, 4, 6, 8, 10, 12, 14};
    const int eidx[8] = {1, 3, 5, 7, 9, 11, 13, 15};
    for (int i = 0; i < 8; ++i) {
        ga.feat[i] = (const float*)d_in[fidx[i]];
        ga.emb[i]  = (const float*)d_in[eidx[i]];
    }
    const float* alpha   = (const float*)d_in[16];
    const float* gumbels = (const float*)d_in[17];
    const float* prelu_a = (const float*)d_in[18];
    const float* w_out   = (const float*)d_in[19];
    const int*   es      = (const int*)d_in[20];

    float* wsf = (float*)d_ws;                               // probs[8] + gstats[128]
    u16* WcTpre = (u16*)((char*)d_ws + 1024);                // [44 tiles][16384] bf16 (32KB/tile)
    u16* wT  = (u16*)((char*)d_ws + 1024 + (size_t)NTILE * 16384 * 2);  // [64][256] bf16
    float* out = (float*)d_out;

    k_prep0<<<1, 256, 0, stream>>>(alpha, gumbels, es, wsf);
    k_prep1<<<NTILE + 1, 256, 0, stream>>>(ga, w_out, wsf, WcTpre, wT);
    k_gemm1<<<(N_ROWS + 63) / 64, 256, 0, stream>>>(ga, WcTpre, wT, prelu_a, out, wsf + 8);
    k_stats<<<1, 64, 0, stream>>>(wsf);
    k_norm<<<(N_ROWS * NCLASS) / 1024, 256, 0, stream>>>(out, wsf);
}